// Round 1
// baseline (122.155 us; speedup 1.0000x reference)
//
#include <hip/hip_runtime.h>

// DCN cross layer, B=16384, D=1024, L=3, fp32.
//   cross = x
//   for i in L: s = dot(cross, W[i]); cross = x*s + bias[i] + cross
//
// Memory-bound: 64 MiB read (x) + 64 MiB write (out). W/bias are 12 KiB each
// -> L1/L2 resident. Strategy: one 64-lane wave per row, cross in registers,
// wave-shuffle dot reduction, no LDS / no barriers.

#define D_DIM 1024
#define N_LAYER 3
#define ROWS_PER_BLOCK 4   // 4 waves * 64 lanes, each wave owns one row

__global__ __launch_bounds__(256) void cross_layer_kernel(
    const float* __restrict__ x,
    const float* __restrict__ W,
    const float* __restrict__ bias,
    float* __restrict__ out,
    int n_rows)
{
    const int wave = threadIdx.x >> 6;   // 0..3
    const int lane = threadIdx.x & 63;   // 0..63
    const int row  = blockIdx.x * ROWS_PER_BLOCK + wave;
    if (row >= n_rows) return;

    // Row layout: 1024 floats = 64 lanes * 4 float4 segments.
    // Segment j: elements [j*256 + lane*4 .. +3]  (coalesced 16B/lane).
    const float4* xr = reinterpret_cast<const float4*>(x + (size_t)row * D_DIM);

    float4 xv[4];   // x row, reused every layer
    float4 cv[4];   // running cross
    #pragma unroll
    for (int j = 0; j < 4; ++j) {
        xv[j] = xr[j * 64 + lane];
        cv[j] = xv[j];
    }

    #pragma unroll
    for (int i = 0; i < N_LAYER; ++i) {
        const float4* wr = reinterpret_cast<const float4*>(W    + i * D_DIM);
        const float4* br = reinterpret_cast<const float4*>(bias + i * D_DIM);

        // per-lane partial dot over this lane's 16 elements
        float p = 0.0f;
        #pragma unroll
        for (int j = 0; j < 4; ++j) {
            const float4 w = wr[j * 64 + lane];
            p += cv[j].x * w.x;
            p += cv[j].y * w.y;
            p += cv[j].z * w.z;
            p += cv[j].w * w.w;
        }

        // 64-lane butterfly reduction (wave = 64 on CDNA4)
        #pragma unroll
        for (int off = 32; off > 0; off >>= 1)
            p += __shfl_xor(p, off, 64);

        // cross = x * s + bias + cross   (all in registers)
        #pragma unroll
        for (int j = 0; j < 4; ++j) {
            const float4 bv = br[j * 64 + lane];
            cv[j].x = fmaf(xv[j].x, p, bv.x + cv[j].x);
            cv[j].y = fmaf(xv[j].y, p, bv.y + cv[j].y);
            cv[j].z = fmaf(xv[j].z, p, bv.z + cv[j].z);
            cv[j].w = fmaf(xv[j].w, p, bv.w + cv[j].w);
        }
    }

    float4* orow = reinterpret_cast<float4*>(out + (size_t)row * D_DIM);
    #pragma unroll
    for (int j = 0; j < 4; ++j)
        orow[j * 64 + lane] = cv[j];
}

extern "C" void kernel_launch(void* const* d_in, const int* in_sizes, int n_in,
                              void* d_out, int out_size, void* d_ws, size_t ws_size,
                              hipStream_t stream)
{
    const float* x    = (const float*)d_in[0];   // (B, D, 1) f32
    const float* W    = (const float*)d_in[1];   // (L, D, 1) f32
    const float* bias = (const float*)d_in[2];   // (L, D, 1) f32
    float* out = (float*)d_out;                  // (B, D, 1) f32

    const int n_rows = in_sizes[0] / D_DIM;      // 16384
    const int blocks = (n_rows + ROWS_PER_BLOCK - 1) / ROWS_PER_BLOCK;  // 4096

    cross_layer_kernel<<<blocks, 256, 0, stream>>>(x, W, bias, out, n_rows);
}